// Round 4
// baseline (62.286 us; speedup 1.0000x reference)
//
#include <hip/hip_runtime.h>
#include <hip/hip_bf16.h>
#include <math.h>

typedef _Float16 half8  __attribute__((ext_vector_type(8)));
typedef _Float16 half2v __attribute__((ext_vector_type(2)));
typedef __fp16   fp16x2 __attribute__((ext_vector_type(2)));
typedef float    f32x4  __attribute__((ext_vector_type(4)));

#define DDIM 128
#define LQ   512
#define NKV  2048
#define KVB  32
#define NIT  16    // chunks per quarter (4 quarters x 16 x 32 = 2048)

union U32H2 { unsigned u; fp16x2 h; };
union H8W   { unsigned u[4]; half8 h; };

__device__ __forceinline__ int swzk(int row) { return (row & 7) << 3; }            // K row-XOR (elem)
__device__ __forceinline__ int swzv(int d)   { return ((d ^ (d >> 4)) & 3) << 3; } // VT row-XOR (elem)

__global__ __launch_bounds__(512, 4)
void gattn(const float* __restrict__ seq, const float* __restrict__ fism,
           float* __restrict__ out)
{
  const int tid  = threadIdx.x;
  const int lane = tid & 63;
  const int wv   = tid >> 6;      // 0..7
  const int wq   = wv & 1;        // q-group (16 rows)
  const int kvq  = wv >> 1;       // KV quarter 0..3
  const int q16  = lane & 15;
  const int g    = lane >> 4;

  // XCD swizzle: 64 consecutive swz per XCD -> 4 whole batches per XCD
  const int swz = (blockIdx.x & 7) * 64 + (blockIdx.x >> 3);
  const int b   = swz >> 4;
  const int qb  = (swz & 15) * 32;

  const float* seqB = seq  + (size_t)b * LQ * DDIM;
  const float* fisB = fism + (size_t)b * NKV * DDIM;
  float*       outB = out  + (size_t)b * LQ * DDIM;

  __shared__ _Float16 Ksh[4][KVB * DDIM];   // per-quarter [32][128], row-XOR swizzled
  __shared__ _Float16 VTsh[4][DDIM * KVB];  // per-quarter [128][32] transposed, swizzled
  __shared__ float    stats[4][2][16][3];   // {m, S, tmax} per (quarter, qgroup, row)

  // ---- Q fragments ----
  half8 qf[4];
  {
    const int qrow = qb + wq * 16 + q16;
    #pragma unroll
    for (int c = 0; c < 4; ++c) {
      const float* p = seqB + (size_t)qrow * DDIM + c * 32 + g * 8;
      float4 a  = *(const float4*)p;
      float4 b2 = *(const float4*)(p + 4);
      half8 h;
      h[0]=(_Float16)a.x;  h[1]=(_Float16)a.y;  h[2]=(_Float16)a.z;  h[3]=(_Float16)a.w;
      h[4]=(_Float16)b2.x; h[5]=(_Float16)b2.y; h[6]=(_Float16)b2.z; h[7]=(_Float16)b2.w;
      qf[c] = h;
    }
  }

  // staging: 512 threads cover 4 quarter-chunks (128 rows total)
  const int sp   = tid >> 3;     // 0..63
  const int dgrp = tid & 7;      // 16-col group
  const int qstg = sp >> 4;      // which quarter buffer this thread fills
  const int spc  = sp & 15;      // rows {2spc, 2spc+1} within chunk

  f32x4 acc[8];
  #pragma unroll
  for (int i = 0; i < 8; ++i) { f32x4 z = {0.f,0.f,0.f,0.f}; acc[i] = z; }

  float m_run = -INFINITY, tmax = -INFINITY, S_run = 0.f;

  auto write_stage = [&](const float4* v) {
    #pragma unroll
    for (int r = 0; r < 2; ++r) {
      const int row = 2*spc + r;
      #pragma unroll
      for (int hh = 0; hh < 2; ++hh) {
        const float4 x = v[r*4 + hh*2];
        const float4 y = v[r*4 + hh*2 + 1];
        half8 h;
        h[0]=(_Float16)x.x; h[1]=(_Float16)x.y; h[2]=(_Float16)x.z; h[3]=(_Float16)x.w;
        h[4]=(_Float16)y.x; h[5]=(_Float16)y.y; h[6]=(_Float16)y.z; h[7]=(_Float16)y.w;
        const int idx = row*DDIM + ((dgrp*16 + hh*8) ^ swzk(row));
        *(half8*)&Ksh[qstg][idx] = h;
      }
    }
    #pragma unroll
    for (int k = 0; k < 16; ++k) {
      const int d = dgrp*16 + k;
      half2v pk;
      pk[0] = (_Float16)(((const float*)&v[k>>2])[k&3]);
      pk[1] = (_Float16)(((const float*)&v[4 + (k>>2)])[k&3]);
      const int idx = d*KVB + ((2*spc) ^ swzv(d));
      *(half2v*)&VTsh[qstg][idx] = pk;
    }
  };

  auto load_glb = [&](float4* v, int t) {
    const float* src = fisB + (size_t)(qstg*(NKV/4) + t*KVB) * DDIM;
    #pragma unroll
    for (int r = 0; r < 2; ++r)
      #pragma unroll
      for (int k = 0; k < 4; ++k)
        v[r*4+k] = *(const float4*)(src + (size_t)(2*spc + r)*DDIM + dgrp*16 + k*4);
  };

  // prologue: stage iter 0
  {
    float4 stg[8];
    load_glb(stg, 0);
    write_stage(stg);
  }

  for (int t = 0; t < NIT; ++t) {
    __syncthreads();                 // A: iter-t buffers ready
    float4 nxt[8];
    const bool have = (t + 1 < NIT);
    if (have) load_glb(nxt, t + 1);  // issue early; latency hides under compute

    // ---- QK^T (swapped) on quarter buffer ----
    f32x4 sv[2];
    #pragma unroll
    for (int ns = 0; ns < 2; ++ns) {
      f32x4 x = {0.f,0.f,0.f,0.f};
      const int row = ns*16 + q16;
      #pragma unroll
      for (int c = 0; c < 4; ++c) {
        const int idx = row*DDIM + ((c*32 + g*8) ^ swzk(row));
        half8 kf = *(const half8*)&Ksh[kvq][idx];
        x = __builtin_amdgcn_mfma_f32_16x16x32_f16(kf, qf[c], x, 0, 0, 0);
      }
      sv[ns] = x;   // S[q=q16][n = 16ns + 4g + i]
    }

    // ---- online power-softmax stats ----
    float cmax = sv[0][0];
    #pragma unroll
    for (int ns = 0; ns < 2; ++ns)
      #pragma unroll
      for (int i = 0; i < 4; ++i)
        cmax = fmaxf(cmax, sv[ns][i]);
    cmax = fmaxf(cmax, __shfl_xor(cmax, 16));
    cmax = fmaxf(cmax, __shfl_xor(cmax, 32));
    tmax = fmaxf(tmax, cmax);
    if (__any(cmax > m_run + 8.f)) {
      const float mn = fmaxf(m_run, cmax);
      const float sc = __expf(m_run - mn);
      S_run *= sc;
      m_run = mn;
      const float s0 = __shfl(sc, (g<<4) | (4*g + 0));
      const float s1 = __shfl(sc, (g<<4) | (4*g + 1));
      const float s2 = __shfl(sc, (g<<4) | (4*g + 2));
      const float s3 = __shfl(sc, (g<<4) | (4*g + 3));
      const f32x4 scv = {s0, s1, s2, s3};
      #pragma unroll
      for (int dsu = 0; dsu < 8; ++dsu) acc[dsu] *= scv;
    }
    float lsum = 0.f;
    #pragma unroll
    for (int ns = 0; ns < 2; ++ns)
      #pragma unroll
      for (int i = 0; i < 4; ++i) {
        const float p = __expf(sv[ns][i] - m_run);
        sv[ns][i] = p;
        lsum += p;
      }
    lsum += __shfl_xor(lsum, 16);
    lsum += __shfl_xor(lsum, 32);
    S_run += lsum;

    // ---- pack P->f16, redistribute, PV ----
    unsigned upk[2][2];
    #pragma unroll
    for (int ns = 0; ns < 2; ++ns) {
      U32H2 u0, u1;
      u0.h = __builtin_amdgcn_cvt_pkrtz(sv[ns][0], sv[ns][1]);
      u1.h = __builtin_amdgcn_cvt_pkrtz(sv[ns][2], sv[ns][3]);
      upk[ns][0] = u0.u; upk[ns][1] = u1.u;
    }
    {
      H8W aw;
      #pragma unroll
      for (int tt = 0; tt < 4; ++tt) {
        const int src = q16 + 16 * ((g & 1) * 2 + (tt >> 1));
        const unsigned lo = (unsigned)__shfl((int)upk[0][tt & 1], src);
        const unsigned hi = (unsigned)__shfl((int)upk[1][tt & 1], src);
        aw.u[tt] = (g < 2) ? lo : hi;
      }
      const half8 pa = aw.h;   // A[q=q16][n = 8g + j]
      #pragma unroll
      for (int dsu = 0; dsu < 8; ++dsu) {
        const int d = dsu*16 + q16;
        const int idx = d*KVB + ((g*8) ^ swzv(d));
        half8 vf = *(const half8*)&VTsh[kvq][idx];
        acc[dsu] = __builtin_amdgcn_mfma_f32_16x16x32_f16(pa, vf, acc[dsu], 0, 0, 0);
      }
    }

    __syncthreads();                 // B: done reading iter t; nxt loads landed
    if (have) write_stage(nxt);
  }

  // ---- 4-way combine ----
  __syncthreads();
  if (kvq != 0) {
    const int rgn = (kvq - 1) * 2 + wq;           // 0..5
    float* base = (rgn < 4) ? ((float*)&Ksh[0][0]  + rgn * 2048)
                            : ((float*)&VTsh[0][0] + (rgn - 4) * 2048);
    float* p = base + lane * 32;
    #pragma unroll
    for (int dsu = 0; dsu < 8; ++dsu)
      *(f32x4*)&p[dsu*4] = acc[dsu];
    if (g == 0) {
      stats[kvq][wq][q16][0] = m_run;
      stats[kvq][wq][q16][1] = S_run;
      stats[kvq][wq][q16][2] = tmax;
    }
  }
  __syncthreads();

  if (kvq == 0) {
    float mj[4], Sj[4], tj[4];
    mj[0] = m_run; Sj[0] = S_run; tj[0] = tmax;
    #pragma unroll
    for (int j = 1; j < 4; ++j) {
      mj[j] = stats[j][wq][q16][0];
      Sj[j] = stats[j][wq][q16][1];
      tj[j] = stats[j][wq][q16][2];
    }
    const float M = fmaxf(fmaxf(tj[0], tj[1]), fmaxf(tj[2], tj[3]));
    float aj[4], den = 0.f;
    #pragma unroll
    for (int j = 0; j < 4; ++j) { aj[j] = __expf(mj[j] - M); den += aj[j] * Sj[j]; }
    const float rs = rsqrtf(den);
    float fr[4][4];
    #pragma unroll
    for (int j = 0; j < 4; ++j) {
      const float fj = aj[j] * rs;
      #pragma unroll
      for (int i = 0; i < 4; ++i)
        fr[j][i] = __shfl(fj, (g<<4) | (4*g + i));
    }
    #pragma unroll
    for (int dsu = 0; dsu < 8; ++dsu) {
      f32x4 av = acc[dsu];
      av *= (f32x4){fr[0][0], fr[0][1], fr[0][2], fr[0][3]};
      #pragma unroll
      for (int j = 1; j < 4; ++j) {
        const int rgn = (j - 1) * 2 + wq;
        const float* base = (rgn < 4) ? ((const float*)&Ksh[0][0]  + rgn * 2048)
                                      : ((const float*)&VTsh[0][0] + (rgn - 4) * 2048);
        const f32x4 pj = *(const f32x4*)&base[lane*32 + dsu*4];
        av += pj * (f32x4){fr[j][0], fr[j][1], fr[j][2], fr[j][3]};
      }
      #pragma unroll
      for (int i = 0; i < 4; ++i) {
        const int qrow = qb + wq*16 + 4*g + i;
        const int d = dsu*16 + q16;
        const float s = seqB[(size_t)qrow * DDIM + d];
        outB[(size_t)qrow * DDIM + d] = 0.5f * s * (1.f + av[i]);
      }
    }
  }
}

extern "C" void kernel_launch(void* const* d_in, const int* in_sizes, int n_in,
                              void* d_out, int out_size, void* d_ws, size_t ws_size,
                              hipStream_t stream) {
  const float* seq  = (const float*)d_in[0];
  const float* fism = (const float*)d_in[1];
  float* out = (float*)d_out;
  gattn<<<dim3(512), dim3(512), 0, stream>>>(seq, fism, out);
}

// Round 5
// 52.405 us; speedup vs baseline: 1.1885x; 1.1885x over previous
//
#include <hip/hip_runtime.h>
#include <hip/hip_bf16.h>
#include <math.h>

typedef _Float16 half8  __attribute__((ext_vector_type(8)));
typedef _Float16 half4v __attribute__((ext_vector_type(4)));
typedef __fp16   fp16x2 __attribute__((ext_vector_type(2)));
typedef float    f32x4  __attribute__((ext_vector_type(4)));

#define DDIM 128
#define LQ   512
#define NKV  2048
#define KVB  64
#define NIT  8     // chunks per quarter: 4 quarters x 8 x 64 = 2048

union U32H2 { unsigned u; fp16x2 h; };
union H8W   { unsigned u[4]; half8 h; };

__device__ __forceinline__ int swzk(int row) { return (row & 7) << 3; }
__device__ __forceinline__ int swzv(int d)   { return ((d ^ (d >> 4)) & 7) << 3; }

__global__ __launch_bounds__(512, 2)
void gattn(const float* __restrict__ seq, const float* __restrict__ fism,
           float* __restrict__ out)
{
  const int tid  = threadIdx.x;
  const int lane = tid & 63;
  const int wv   = tid >> 6;      // 0..7
  const int wq   = wv & 1;        // q-group: 32 rows
  const int kvq  = wv >> 1;       // KV quarter 0..3
  const int q16  = lane & 15;
  const int g    = lane >> 4;

  // XCD swizzle: 32 consecutive swz per XCD -> 4 whole batches per XCD
  const int swz = (blockIdx.x & 7) * 32 + (blockIdx.x >> 3);
  const int b   = swz >> 3;
  const int qb  = (swz & 7) * 64;

  const float* seqB = seq  + (size_t)b * LQ * DDIM;
  const float* fisB = fism + (size_t)b * NKV * DDIM;
  float*       outB = out  + (size_t)b * LQ * DDIM;

  __shared__ _Float16 Ksh[4][KVB * DDIM];   // per-quarter [64][128], row-XOR swizzled
  __shared__ _Float16 VTsh[4][DDIM * KVB];  // per-quarter [128][64] transposed, swizzled
  __shared__ float    stats[4][2][2][16][3];

  // ---- Q fragments: 2 q-sets of 16 rows each ----
  half8 qf[2][4];
  #pragma unroll
  for (int qs = 0; qs < 2; ++qs) {
    const int qrow = qb + wq * 32 + qs * 16 + q16;
    #pragma unroll
    for (int c = 0; c < 4; ++c) {
      const float* p = seqB + (size_t)qrow * DDIM + c * 32 + g * 8;
      float4 a  = *(const float4*)p;
      float4 b2 = *(const float4*)(p + 4);
      half8 h;
      h[0]=(_Float16)a.x;  h[1]=(_Float16)a.y;  h[2]=(_Float16)a.z;  h[3]=(_Float16)a.w;
      h[4]=(_Float16)b2.x; h[5]=(_Float16)b2.y; h[6]=(_Float16)b2.z; h[7]=(_Float16)b2.w;
      qf[qs][c] = h;
    }
  }

  // staging: 512 threads cover 4 quarter-chunks (256 rows) per iteration.
  // thread: quarter qstg, rows {4spc..4spc+3}, cols [dgrp*16, +16)
  const int sp   = tid >> 3;     // 0..63
  const int dgrp = tid & 7;
  const int qstg = sp >> 4;      // 0..3
  const int spc  = sp & 15;      // 4 rows each

  f32x4 acc[2][8];
  #pragma unroll
  for (int qs = 0; qs < 2; ++qs)
    #pragma unroll
    for (int i = 0; i < 8; ++i) { f32x4 z = {0.f,0.f,0.f,0.f}; acc[qs][i] = z; }

  float m_run[2] = {-INFINITY, -INFINITY};
  float tmax[2]  = {-INFINITY, -INFINITY};
  float S_run[2] = {0.f, 0.f};

  auto write_stage = [&](const float4* v) {
    #pragma unroll
    for (int r = 0; r < 4; ++r) {
      const int row = 4*spc + r;
      #pragma unroll
      for (int hh = 0; hh < 2; ++hh) {
        const float4 x = v[r*4 + hh*2];
        const float4 y = v[r*4 + hh*2 + 1];
        half8 h;
        h[0]=(_Float16)x.x; h[1]=(_Float16)x.y; h[2]=(_Float16)x.z; h[3]=(_Float16)x.w;
        h[4]=(_Float16)y.x; h[5]=(_Float16)y.y; h[6]=(_Float16)y.z; h[7]=(_Float16)y.w;
        const int idx = row*DDIM + ((dgrp*16 + hh*8) ^ swzk(row));
        *(half8*)&Ksh[qstg][idx] = h;
      }
    }
    #pragma unroll
    for (int k = 0; k < 16; ++k) {
      const int d = dgrp*16 + k;
      half4v pk;
      #pragma unroll
      for (int r = 0; r < 4; ++r)
        pk[r] = (_Float16)(((const float*)&v[r*4 + (k>>2)])[k&3]);
      const int idx = d*KVB + ((4*spc) ^ swzv(d));
      *(half4v*)&VTsh[qstg][idx] = pk;
    }
  };

  auto load_glb = [&](float4* v, int t) {
    const float* src = fisB + (size_t)(qstg*(NKV/4) + t*KVB) * DDIM;
    #pragma unroll
    for (int r = 0; r < 4; ++r)
      #pragma unroll
      for (int k = 0; k < 4; ++k)
        v[r*4+k] = *(const float4*)(src + (size_t)(4*spc + r)*DDIM + dgrp*16 + k*4);
  };

  { // prologue
    float4 stg[16];
    load_glb(stg, 0);
    write_stage(stg);
  }

  for (int t = 0; t < NIT; ++t) {
    __syncthreads();                 // A: iter-t buffers ready
    float4 nxt[16];
    const bool have = (t + 1 < NIT);
    if (have) load_glb(nxt, t + 1);

    // ---- QK^T (swapped), K-frag shared across both q-sets ----
    f32x4 sv[2][4];
    #pragma unroll
    for (int ns = 0; ns < 4; ++ns) {
      f32x4 x0 = {0.f,0.f,0.f,0.f}, x1 = {0.f,0.f,0.f,0.f};
      const int row = ns*16 + q16;
      #pragma unroll
      for (int c = 0; c < 4; ++c) {
        const int idx = row*DDIM + ((c*32 + g*8) ^ swzk(row));
        half8 kf = *(const half8*)&Ksh[kvq][idx];
        x0 = __builtin_amdgcn_mfma_f32_16x16x32_f16(kf, qf[0][c], x0, 0, 0, 0);
        x1 = __builtin_amdgcn_mfma_f32_16x16x32_f16(kf, qf[1][c], x1, 0, 0, 0);
      }
      sv[0][ns] = x0; sv[1][ns] = x1;
    }

    // ---- online power-softmax stats (independent per q-set -> ILP) ----
    unsigned upk[2][4][2];
    #pragma unroll
    for (int qs = 0; qs < 2; ++qs) {
      float cmax = sv[qs][0][0];
      #pragma unroll
      for (int ns = 0; ns < 4; ++ns)
        #pragma unroll
        for (int i = 0; i < 4; ++i)
          cmax = fmaxf(cmax, sv[qs][ns][i]);
      cmax = fmaxf(cmax, __shfl_xor(cmax, 16));
      cmax = fmaxf(cmax, __shfl_xor(cmax, 32));
      tmax[qs] = fmaxf(tmax[qs], cmax);
      if (__any(cmax > m_run[qs] + 8.f)) {
        const float mn = fmaxf(m_run[qs], cmax);
        const float sc = __expf(m_run[qs] - mn);
        S_run[qs] *= sc;
        m_run[qs] = mn;
        const float s0 = __shfl(sc, (g<<4) | (4*g + 0));
        const float s1 = __shfl(sc, (g<<4) | (4*g + 1));
        const float s2 = __shfl(sc, (g<<4) | (4*g + 2));
        const float s3 = __shfl(sc, (g<<4) | (4*g + 3));
        const f32x4 scv = {s0, s1, s2, s3};
        #pragma unroll
        for (int dsu = 0; dsu < 8; ++dsu) acc[qs][dsu] *= scv;
      }
      float lsum = 0.f;
      #pragma unroll
      for (int ns = 0; ns < 4; ++ns)
        #pragma unroll
        for (int i = 0; i < 4; ++i) {
          const float p = __expf(sv[qs][ns][i] - m_run[qs]);
          sv[qs][ns][i] = p;
          lsum += p;
        }
      lsum += __shfl_xor(lsum, 16);
      lsum += __shfl_xor(lsum, 32);
      S_run[qs] += lsum;

      #pragma unroll
      for (int ns = 0; ns < 4; ++ns) {
        U32H2 u0, u1;
        u0.h = __builtin_amdgcn_cvt_pkrtz(sv[qs][ns][0], sv[qs][ns][1]);
        u1.h = __builtin_amdgcn_cvt_pkrtz(sv[qs][ns][2], sv[qs][ns][3]);
        upk[qs][ns][0] = u0.u; upk[qs][ns][1] = u1.u;
      }
    }

    // ---- redistribute P, PV (V-frag shared across q-sets) ----
    #pragma unroll
    for (int c = 0; c < 2; ++c) {
      H8W aw0, aw1;
      #pragma unroll
      for (int tt = 0; tt < 4; ++tt) {
        const int src = q16 + 16 * ((g & 1) * 2 + (tt >> 1));
        const unsigned lo0 = (unsigned)__shfl((int)upk[0][2*c  ][tt & 1], src);
        const unsigned hi0 = (unsigned)__shfl((int)upk[0][2*c+1][tt & 1], src);
        const unsigned lo1 = (unsigned)__shfl((int)upk[1][2*c  ][tt & 1], src);
        const unsigned hi1 = (unsigned)__shfl((int)upk[1][2*c+1][tt & 1], src);
        aw0.u[tt] = (g < 2) ? lo0 : hi0;
        aw1.u[tt] = (g < 2) ? lo1 : hi1;
      }
      const half8 pa0 = aw0.h, pa1 = aw1.h;
      #pragma unroll
      for (int dsu = 0; dsu < 8; ++dsu) {
        const int d = dsu*16 + q16;
        const int idx = d*KVB + ((c*32 + g*8) ^ swzv(d));
        half8 vf = *(const half8*)&VTsh[kvq][idx];
        acc[0][dsu] = __builtin_amdgcn_mfma_f32_16x16x32_f16(pa0, vf, acc[0][dsu], 0, 0, 0);
        acc[1][dsu] = __builtin_amdgcn_mfma_f32_16x16x32_f16(pa1, vf, acc[1][dsu], 0, 0, 0);
      }
    }

    __syncthreads();                 // B: done reading iter t
    if (have) write_stage(nxt);
  }

  __syncthreads();

  // ---- 4-way combine: quarters 1..3 spill via LDS (reusing buffers) ----
  float* Kf  = (float*)&Ksh[0][0];   // 16384 floats: regions 0..7 (2048 each)
  float* VTf = (float*)&VTsh[0][0];  // regions 8..11
  if (kvq != 0) {
    #pragma unroll
    for (int qs = 0; qs < 2; ++qs) {
      const int rgn = (((kvq - 1) * 2 + wq) << 1) | qs;
      float* base = (rgn < 8) ? (Kf + rgn * 2048) : (VTf + (rgn - 8) * 2048);
      float* p = base + lane * 32;
      #pragma unroll
      for (int dsu = 0; dsu < 8; ++dsu)
        *(f32x4*)&p[(dsu * 4) ^ ((lane & 7) << 2)] = acc[qs][dsu];
      if (g == 0) {
        stats[kvq][wq][qs][q16][0] = m_run[qs];
        stats[kvq][wq][qs][q16][1] = S_run[qs];
        stats[kvq][wq][qs][q16][2] = tmax[qs];
      }
    }
  }
  __syncthreads();

  if (kvq == 0) {
    #pragma unroll
    for (int qs = 0; qs < 2; ++qs) {
      float mj[4], Sj[4], tj[4];
      mj[0] = m_run[qs]; Sj[0] = S_run[qs]; tj[0] = tmax[qs];
      #pragma unroll
      for (int j = 1; j < 4; ++j) {
        mj[j] = stats[j][wq][qs][q16][0];
        Sj[j] = stats[j][wq][qs][q16][1];
        tj[j] = stats[j][wq][qs][q16][2];
      }
      const float M = fmaxf(fmaxf(tj[0], tj[1]), fmaxf(tj[2], tj[3]));
      float aj[4], den = 0.f;
      #pragma unroll
      for (int j = 0; j < 4; ++j) { aj[j] = __expf(mj[j] - M); den += aj[j] * Sj[j]; }
      const float rs = rsqrtf(den);
      float fr[4][4];
      #pragma unroll
      for (int j = 0; j < 4; ++j) {
        const float fj = aj[j] * rs;
        #pragma unroll
        for (int i = 0; i < 4; ++i)
          fr[j][i] = __shfl(fj, (g<<4) | (4*g + i));
      }
      #pragma unroll
      for (int dsu = 0; dsu < 8; ++dsu) {
        f32x4 av = acc[qs][dsu];
        av *= (f32x4){fr[0][0], fr[0][1], fr[0][2], fr[0][3]};
        #pragma unroll
        for (int j = 1; j < 4; ++j) {
          const int rgn = (((j - 1) * 2 + wq) << 1) | qs;
          const float* base = (rgn < 8) ? (Kf + rgn * 2048) : (VTf + (rgn - 8) * 2048);
          const f32x4 pj = *(const f32x4*)&base[lane*32 + ((dsu * 4) ^ ((lane & 7) << 2))];
          av += pj * (f32x4){fr[j][0], fr[j][1], fr[j][2], fr[j][3]};
        }
        #pragma unroll
        for (int i = 0; i < 4; ++i) {
          const int qrow = qb + wq*32 + qs*16 + 4*g + i;
          const int d = dsu*16 + q16;
          const float s = seqB[(size_t)qrow * DDIM + d];
          outB[(size_t)qrow * DDIM + d] = 0.5f * s * (1.f + av[i]);
        }
      }
    }
  }
}

extern "C" void kernel_launch(void* const* d_in, const int* in_sizes, int n_in,
                              void* d_out, int out_size, void* d_ws, size_t ws_size,
                              hipStream_t stream) {
  const float* seq  = (const float*)d_in[0];
  const float* fism = (const float*)d_in[1];
  float* out = (float*)d_out;
  gattn<<<dim3(256), dim3(512), 0, stream>>>(seq, fism, out);
}